// Round 2
// baseline (641.982 us; speedup 1.0000x reference)
//
#include <hip/hip_runtime.h>
#include <math.h>

// ---------------------------------------------------------------------------
// DecoderLayer fused implementation (MI355X / gfx950)
//   K0: convert weights fp32 -> bf16 into ws (layouts already [n][k] row-major)
//   K1: per-node message MLP. RESTRUCTURED: 1 node / 256-thread block,
//       phase 1 is BARRIER-FREE — A-fragments (row=c15, k=ks*32+q*8..+8) are
//       loaded per-lane directly from h_V/h_E as 2x float4, converted with
//       v_cvt_pk_bf16_f32, double-buffered one K-step ahead. No staging LDS.
//       Phases 2/3 via small LDS (m1/m2), 3 barriers total per block.
//   K2: FFN (128->512->128) + LN2 + mask_V
// ---------------------------------------------------------------------------

typedef __bf16 bf16;
typedef __attribute__((ext_vector_type(8))) __bf16 bf16x8;
typedef __attribute__((ext_vector_type(4))) __bf16 bf16x4;
typedef __attribute__((ext_vector_type(4))) float f32x4;

__device__ __forceinline__ bf16 f2bf(float f) {
    unsigned u = __builtin_bit_cast(unsigned, f);
    u += 0x7FFFu + ((u >> 16) & 1u);           // RTNE
    unsigned short s = (unsigned short)(u >> 16);
    return __builtin_bit_cast(bf16, s);
}

// pack two fp32 -> two bf16 (RTNE), one instruction
__device__ __forceinline__ unsigned cvt_pk_bf16(float lo, float hi) {
    unsigned r;
    asm("v_cvt_pk_bf16_f32 %0, %1, %2" : "=v"(r) : "v"(lo), "v"(hi));
    return r;
}

// 8 consecutive fp32 (as two float4) -> bf16x8 fragment
__device__ __forceinline__ bf16x8 mkfrag(float4 a, float4 b) {
    uint4 u;
    u.x = cvt_pk_bf16(a.x, a.y);
    u.y = cvt_pk_bf16(a.z, a.w);
    u.z = cvt_pk_bf16(b.x, b.y);
    u.w = cvt_pk_bf16(b.z, b.w);
    return __builtin_bit_cast(bf16x8, u);
}

__device__ __forceinline__ float gelu_exact(float x) {
    return 0.5f * x * (1.0f + erff(x * 0.70710678118654752f));
}

__device__ __forceinline__ f32x4 mfma16(bf16x8 a, bf16x8 b, f32x4 c) {
    return __builtin_amdgcn_mfma_f32_16x16x32_bf16(a, b, c, 0, 0, 0);
}

// ws layout (bf16 elements unless noted):
//   W1b  @ 0       : 128*512 = 65536
//   W2b  @ 65536   : 128*128 = 16384
//   W3b  @ 81920   : 128*128 = 16384
//   Winb @ 98304   : 512*128 = 65536
//   Woutb@ 163840  : 128*512 = 65536   (total 229376 bf16 = 458752 B)
//   h1   @ byte 458752 : 4096*128 fp32 = 2 MB
#define WS_W2   65536
#define WS_W3   81920
#define WS_WIN  98304
#define WS_WOUT 163840
#define WS_TOTAL_W 229376
#define WS_H1_BYTES 458752

// ---------------------------------------------------------------------------
__global__ void convert_weights(const float* __restrict__ W1, const float* __restrict__ W2,
                                const float* __restrict__ W3, const float* __restrict__ Win,
                                const float* __restrict__ Wout, bf16* __restrict__ ws) {
    int i = blockIdx.x * 256 + threadIdx.x;
    if (i < WS_W2)              ws[i] = f2bf(W1[i]);
    else if (i < WS_W3)         ws[i] = f2bf(W2[i - WS_W2]);
    else if (i < WS_WIN)        ws[i] = f2bf(W3[i - WS_W3]);
    else if (i < WS_WOUT)       ws[i] = f2bf(Win[i - WS_WIN]);
    else if (i < WS_TOTAL_W)    ws[i] = f2bf(Wout[i - WS_WOUT]);
}

// ---------------------------------------------------------------------------
// K1: 1 node per block (48 edge rows = 3 m-tiles), 256 threads (4 waves).
//   wave wv owns output cols [wv*32, wv*32+32): wcol0 = wv*32+c15, wcol1 = +16.
__global__ __launch_bounds__(256, 3)
void msg_kernel(const float* __restrict__ h_V, const float* __restrict__ h_E,
                const float* __restrict__ mask_attend,
                const bf16* __restrict__ W1b, const bf16* __restrict__ W2b,
                const bf16* __restrict__ W3b,
                const float* __restrict__ b1, const float* __restrict__ b2,
                const float* __restrict__ b3,
                const float* __restrict__ ln1g, const float* __restrict__ ln1b,
                float* __restrict__ h1out) {
    __shared__ __align__(16) bf16  m1[48 * 136];   // 13056 B
    __shared__ __align__(16) bf16  m2[48 * 136];   // 13056 B
    __shared__ __align__(16) float tbuf[128];      //   512 B

    const int tid  = threadIdx.x;
    const int wv   = tid >> 6;
    const int lane = tid & 63;
    const int q    = lane >> 4;      // quad 0..3
    const int c15  = lane & 15;
    const int g    = blockIdx.x;     // node id (0..4095)
    const int wcol0 = wv * 32 + c15;
    const int wcol1 = wcol0 + 16;

    // per-lane A-operand bases (row = mt*16 + c15 of this node's 48 edges)
    const float* pE0 = h_E + (size_t)(g * 48 + c15) * 384 + q * 8;
    const float* pE1 = pE0 + (size_t)16 * 384;
    const float* pE2 = pE0 + (size_t)32 * 384;
    const float* pV  = h_V + (size_t)g * 128 + q * 8;   // broadcast row (all 48 rows equal)

    f32x4 zero = {0.f, 0.f, 0.f, 0.f};
    f32x4 acc00 = zero, acc01 = zero, acc10 = zero, acc11 = zero, acc20 = zero, acc21 = zero;

#define LD_W1(w0_, w1_, ks_)                                                        \
    {                                                                               \
        w0_ = *(const bf16x8*)(W1b + (size_t)wcol0 * 512 + (ks_) * 32 + q * 8);     \
        w1_ = *(const bf16x8*)(W1b + (size_t)wcol1 * 512 + (ks_) * 32 + q * 8);     \
    }
#define LD_E(e0_, e1_, ks_)                                                         \
    {                                                                               \
        e0_##0 = *(const float4*)(pE0 + ((ks_) - 4) * 32);                          \
        e1_##0 = *(const float4*)(pE0 + ((ks_) - 4) * 32 + 4);                      \
        e0_##1 = *(const float4*)(pE1 + ((ks_) - 4) * 32);                          \
        e1_##1 = *(const float4*)(pE1 + ((ks_) - 4) * 32 + 4);                      \
        e0_##2 = *(const float4*)(pE2 + ((ks_) - 4) * 32);                          \
        e1_##2 = *(const float4*)(pE2 + ((ks_) - 4) * 32 + 4);                      \
    }
#define MFMA6(f0_, f1_, f2_, wc0_, wc1_)                                            \
    {                                                                               \
        __builtin_amdgcn_s_setprio(1);                                              \
        acc00 = mfma16(f0_, wc0_, acc00); acc01 = mfma16(f0_, wc1_, acc01);         \
        acc10 = mfma16(f1_, wc0_, acc10); acc11 = mfma16(f1_, wc1_, acc11);         \
        acc20 = mfma16(f2_, wc0_, acc20); acc21 = mfma16(f2_, wc1_, acc21);         \
        __builtin_amdgcn_s_setprio(0);                                              \
    }
    // h_V step: all 48 rows identical -> one broadcast fragment feeds all 3 m-tiles
#define STEP_V(v0_, v1_, wc0_, wc1_, wn0_, wn1_, ksn_, dlw_)                        \
    {                                                                               \
        if (dlw_) LD_W1(wn0_, wn1_, ksn_);                                          \
        bf16x8 f_ = mkfrag(v0_, v1_);                                               \
        MFMA6(f_, f_, f_, wc0_, wc1_);                                              \
    }
    // h_E step: per-mt fragments; prefetch next K-step (E + W) before compute
#define STEP_E(c0_, c1_, n0_, n1_, wc0_, wc1_, wn0_, wn1_, ksn_, dl_)               \
    {                                                                               \
        if (dl_) { LD_E(n0_, n1_, ksn_); LD_W1(wn0_, wn1_, ksn_); }                 \
        bf16x8 f0_ = mkfrag(c0_##0, c1_##0);                                        \
        bf16x8 f1_ = mkfrag(c0_##1, c1_##1);                                        \
        bf16x8 f2_ = mkfrag(c0_##2, c1_##2);                                        \
        MFMA6(f0_, f1_, f2_, wc0_, wc1_);                                           \
    }

    // ---------------- phase 1 (barrier-free) ----------------
    {
        bf16x8 wa0, wa1, wb0, wb1;
        float4 ea00, ea01, ea02, ea10, ea11, ea12;   // E buffer A (e0: first half, e1: second)
        float4 eb00, eb01, eb02, eb10, eb11, eb12;   // E buffer B
        float4 v00, v10, v01, v11, v02, v12, v03, v13;

        LD_W1(wa0, wa1, 0);
        v00 = *(const float4*)(pV + 0 * 32);  v10 = *(const float4*)(pV + 0 * 32 + 4);
        v01 = *(const float4*)(pV + 1 * 32);  v11 = *(const float4*)(pV + 1 * 32 + 4);
        v02 = *(const float4*)(pV + 2 * 32);  v12 = *(const float4*)(pV + 2 * 32 + 4);
        v03 = *(const float4*)(pV + 3 * 32);  v13 = *(const float4*)(pV + 3 * 32 + 4);
        LD_E(ea0, ea1, 4);                   // prefetch first h_E K-step

        STEP_V(v00, v10, wa0, wa1, wb0, wb1, 1, 1);   // ks0
        STEP_V(v01, v11, wb0, wb1, wa0, wa1, 2, 1);   // ks1
        STEP_V(v02, v12, wa0, wa1, wb0, wb1, 3, 1);   // ks2
        STEP_V(v03, v13, wb0, wb1, wa0, wa1, 4, 1);   // ks3  (loads W(4) -> wa)

        STEP_E(ea0, ea1, eb0, eb1, wa0, wa1, wb0, wb1,  5, 1);   // ks4
        STEP_E(eb0, eb1, ea0, ea1, wb0, wb1, wa0, wa1,  6, 1);   // ks5
        STEP_E(ea0, ea1, eb0, eb1, wa0, wa1, wb0, wb1,  7, 1);   // ks6
        STEP_E(eb0, eb1, ea0, ea1, wb0, wb1, wa0, wa1,  8, 1);   // ks7
        STEP_E(ea0, ea1, eb0, eb1, wa0, wa1, wb0, wb1,  9, 1);   // ks8
        STEP_E(eb0, eb1, ea0, ea1, wb0, wb1, wa0, wa1, 10, 1);   // ks9
        STEP_E(ea0, ea1, eb0, eb1, wa0, wa1, wb0, wb1, 11, 1);   // ks10
        STEP_E(eb0, eb1, ea0, ea1, wb0, wb1, wa0, wa1, 12, 1);   // ks11
        STEP_E(ea0, ea1, eb0, eb1, wa0, wa1, wb0, wb1, 13, 1);   // ks12
        STEP_E(eb0, eb1, ea0, ea1, wb0, wb1, wa0, wa1, 14, 1);   // ks13
        STEP_E(ea0, ea1, eb0, eb1, wa0, wa1, wb0, wb1, 15, 1);   // ks14
        STEP_E(eb0, eb1, ea0, ea1, wb0, wb1, wa0, wa1, 16, 0);   // ks15 (no prefetch)
    }
#undef STEP_E
#undef STEP_V
#undef LD_E
#undef LD_W1

    // epilogue 1: bias + gelu -> m1   (C/D layout: row = q*4+reg, col = c15)
#define EPI(dst_, accA_, accB_, mt_, bb0_, bb1_)                                    \
    {                                                                               \
        _Pragma("unroll")                                                           \
        for (int r = 0; r < 4; ++r) {                                               \
            const int row_ = (mt_) * 16 + q * 4 + r;                                \
            dst_[row_ * 136 + wcol0] = f2bf(gelu_exact(accA_[r] + bb0_));           \
            dst_[row_ * 136 + wcol1] = f2bf(gelu_exact(accB_[r] + bb1_));           \
        }                                                                           \
    }
    {
        const float bb0 = b1[wcol0];
        const float bb1 = b1[wcol1];
        EPI(m1, acc00, acc01, 0, bb0, bb1);
        EPI(m1, acc10, acc11, 1, bb0, bb1);
        EPI(m1, acc20, acc21, 2, bb0, bb1);
    }
    __syncthreads();

    // ---------------- phase 2 ----------------
    acc00 = zero; acc01 = zero; acc10 = zero; acc11 = zero; acc20 = zero; acc21 = zero;
    __builtin_amdgcn_s_setprio(1);
#pragma unroll
    for (int s = 0; s < 4; ++s) {
        const bf16x8 w0 = *(const bf16x8*)(W2b + (size_t)wcol0 * 128 + s * 32 + q * 8);
        const bf16x8 w1 = *(const bf16x8*)(W2b + (size_t)wcol1 * 128 + s * 32 + q * 8);
        bf16x8 a0 = *(const bf16x8*)(m1 + (0 * 16 + c15) * 136 + s * 32 + q * 8);
        bf16x8 a1 = *(const bf16x8*)(m1 + (1 * 16 + c15) * 136 + s * 32 + q * 8);
        bf16x8 a2 = *(const bf16x8*)(m1 + (2 * 16 + c15) * 136 + s * 32 + q * 8);
        acc00 = mfma16(a0, w0, acc00); acc01 = mfma16(a0, w1, acc01);
        acc10 = mfma16(a1, w0, acc10); acc11 = mfma16(a1, w1, acc11);
        acc20 = mfma16(a2, w0, acc20); acc21 = mfma16(a2, w1, acc21);
    }
    __builtin_amdgcn_s_setprio(0);
    {
        const float bb0 = b2[wcol0];
        const float bb1 = b2[wcol1];
        EPI(m2, acc00, acc01, 0, bb0, bb1);
        EPI(m2, acc10, acc11, 1, bb0, bb1);
        EPI(m2, acc20, acc21, 2, bb0, bb1);
    }
#undef EPI
    __syncthreads();

    // ---------------- phase 3 ----------------
    acc00 = zero; acc01 = zero; acc10 = zero; acc11 = zero; acc20 = zero; acc21 = zero;
    __builtin_amdgcn_s_setprio(1);
#pragma unroll
    for (int s = 0; s < 4; ++s) {
        const bf16x8 w0 = *(const bf16x8*)(W3b + (size_t)wcol0 * 128 + s * 32 + q * 8);
        const bf16x8 w1 = *(const bf16x8*)(W3b + (size_t)wcol1 * 128 + s * 32 + q * 8);
        bf16x8 a0 = *(const bf16x8*)(m2 + (0 * 16 + c15) * 136 + s * 32 + q * 8);
        bf16x8 a1 = *(const bf16x8*)(m2 + (1 * 16 + c15) * 136 + s * 32 + q * 8);
        bf16x8 a2 = *(const bf16x8*)(m2 + (2 * 16 + c15) * 136 + s * 32 + q * 8);
        acc00 = mfma16(a0, w0, acc00); acc01 = mfma16(a0, w1, acc01);
        acc10 = mfma16(a1, w0, acc10); acc11 = mfma16(a1, w1, acc11);
        acc20 = mfma16(a2, w0, acc20); acc21 = mfma16(a2, w1, acc21);
    }
    __builtin_amdgcn_s_setprio(0);

    // masked sum over the node's 48 edges
    {
        const float bb0 = b3[wcol0];
        const float bb1 = b3[wcol1];
        float s0 = 0.f, s1 = 0.f;
#pragma unroll
        for (int r = 0; r < 4; ++r) {
            {
                const int row = 0 * 16 + q * 4 + r;
                const float mv = mask_attend[(size_t)g * 48 + row];
                s0 += (acc00[r] + bb0) * mv;  s1 += (acc01[r] + bb1) * mv;
            }
            {
                const int row = 1 * 16 + q * 4 + r;
                const float mv = mask_attend[(size_t)g * 48 + row];
                s0 += (acc10[r] + bb0) * mv;  s1 += (acc11[r] + bb1) * mv;
            }
            {
                const int row = 2 * 16 + q * 4 + r;
                const float mv = mask_attend[(size_t)g * 48 + row];
                s0 += (acc20[r] + bb0) * mv;  s1 += (acc21[r] + bb1) * mv;
            }
        }
#pragma unroll
        for (int off = 16; off <= 32; off <<= 1) {
            s0 += __shfl_xor(s0, off);
            s1 += __shfl_xor(s1, off);
        }
        if (lane < 16) {
            tbuf[wcol0] = h_V[(size_t)g * 128 + wcol0] + s0 * (1.0f / 30.0f);
            tbuf[wcol1] = h_V[(size_t)g * 128 + wcol1] + s1 * (1.0f / 30.0f);
        }
    }
    __syncthreads();

    // LN1: wave 0 handles the node
    if (wv == 0) {
        const float x0 = tbuf[lane];
        const float x1 = tbuf[64 + lane];
        float sm = x0 + x1, sq = x0 * x0 + x1 * x1;
#pragma unroll
        for (int off = 1; off < 64; off <<= 1) { sm += __shfl_xor(sm, off); sq += __shfl_xor(sq, off); }
        const float mu  = sm * (1.0f / 128.0f);
        const float var = sq * (1.0f / 128.0f) - mu * mu;
        const float inv = rsqrtf(var + 1e-5f);
        h1out[(size_t)g * 128 + lane]      = (x0 - mu) * inv * ln1g[lane]      + ln1b[lane];
        h1out[(size_t)g * 128 + 64 + lane] = (x1 - mu) * inv * ln1g[64 + lane] + ln1b[64 + lane];
    }
}

// ---------------------------------------------------------------------------
// K2: FFN + LN2 + mask_V. 16 rows per block, 256 blocks, 256 threads.
__global__ __launch_bounds__(256, 2)
void ffn_kernel(const float* __restrict__ h1, const bf16* __restrict__ Winb,
                const bf16* __restrict__ Woutb,
                const float* __restrict__ bin, const float* __restrict__ bout,
                const float* __restrict__ ln2g, const float* __restrict__ ln2b,
                const float* __restrict__ mask_V, float* __restrict__ out) {
    __shared__ __align__(16) bf16  a2[16 * 136];
    __shared__ __align__(16) bf16  ff[16 * 264];
    __shared__ __align__(16) float tb[16 * 132];

    const int tid  = threadIdx.x;
    const int wave = tid >> 6;
    const int lane = tid & 63;
    const int q    = lane >> 4;
    const int c15  = lane & 15;
    const int r0g  = blockIdx.x * 16;

    // stage h1 rows -> bf16 LDS
#pragma unroll
    for (int it = 0; it < 2; ++it) {
        const int idx = it * 256 + tid;      // 0..511 float4s
        const int row = idx >> 5;
        const int c4  = idx & 31;
        const float4 v = *(const float4*)(h1 + (size_t)(r0g + row) * 128 + c4 * 4);
        uint2 w;
        w.x = cvt_pk_bf16(v.x, v.y);
        w.y = cvt_pk_bf16(v.z, v.w);
        *(uint2*)(a2 + row * 136 + c4 * 4) = w;
    }

    f32x4 zero = {0.f, 0.f, 0.f, 0.f};
    f32x4 accB[2]; accB[0] = zero; accB[1] = zero;

    for (int p = 0; p < 2; ++p) {
        __syncthreads();
        // GEMM-a: [16,128] @ Win^T half -> gelu -> ff[16,256]
        f32x4 accA[4];
#pragma unroll
        for (int i = 0; i < 4; ++i) accA[i] = zero;
        __builtin_amdgcn_s_setprio(1);
#pragma unroll
        for (int s = 0; s < 4; ++s) {
            bf16x8 af = *(const bf16x8*)(a2 + c15 * 136 + s * 32 + q * 8);
#pragma unroll
            for (int nt = 0; nt < 4; ++nt) {
                const int n = p * 256 + wave * 64 + nt * 16 + c15;
                bf16x8 wb = *(const bf16x8*)(Winb + (size_t)n * 128 + s * 32 + q * 8);
                accA[nt] = mfma16(af, wb, accA[nt]);
            }
        }
        __builtin_amdgcn_s_setprio(0);
#pragma unroll
        for (int nt = 0; nt < 4; ++nt) {
            const int colL = wave * 64 + nt * 16 + c15;
            const float bb = bin[p * 256 + colL];
#pragma unroll
            for (int r = 0; r < 4; ++r) {
                const int row = q * 4 + r;
                ff[row * 264 + colL] = f2bf(gelu_exact(accA[nt][r] + bb));
            }
        }
        __syncthreads();
        // GEMM-b: ff[16,256] @ Wout^T half -> accB
        __builtin_amdgcn_s_setprio(1);
#pragma unroll
        for (int s = 0; s < 8; ++s) {
            bf16x8 af = *(const bf16x8*)(ff + c15 * 264 + s * 32 + q * 8);
#pragma unroll
            for (int nt = 0; nt < 2; ++nt) {
                const int n = wave * 32 + nt * 16 + c15;
                bf16x8 wb = *(const bf16x8*)(Woutb + (size_t)n * 512 + p * 256 + s * 32 + q * 8);
                accB[nt] = mfma16(af, wb, accB[nt]);
            }
        }
        __builtin_amdgcn_s_setprio(0);
    }
    // residual + bias -> tb
#pragma unroll
    for (int nt = 0; nt < 2; ++nt) {
        const int col = wave * 32 + nt * 16 + c15;
        const float bb = bout[col];
#pragma unroll
        for (int r = 0; r < 4; ++r) {
            const int row = q * 4 + r;
            tb[row * 132 + col] = accB[nt][r] + bb + h1[(size_t)(r0g + row) * 128 + col];
        }
    }
    __syncthreads();
    // LN2 + mask: wave w handles rows 4w..4w+3
#pragma unroll
    for (int rr = 0; rr < 4; ++rr) {
        const int row = wave * 4 + rr;
        const float x0 = tb[row * 132 + lane];
        const float x1 = tb[row * 132 + 64 + lane];
        float sm = x0 + x1, sq = x0 * x0 + x1 * x1;
#pragma unroll
        for (int off = 1; off < 64; off <<= 1) { sm += __shfl_xor(sm, off); sq += __shfl_xor(sq, off); }
        const float mu  = sm * (1.0f / 128.0f);
        const float var = sq * (1.0f / 128.0f) - mu * mu;
        const float inv = rsqrtf(var + 1e-5f);
        const int g = r0g + row;
        const float mv = mask_V[g];
        out[(size_t)g * 128 + lane]      = mv * ((x0 - mu) * inv * ln2g[lane]      + ln2b[lane]);
        out[(size_t)g * 128 + 64 + lane] = mv * ((x1 - mu) * inv * ln2g[64 + lane] + ln2b[64 + lane]);
    }
}

// ---------------------------------------------------------------------------
extern "C" void kernel_launch(void* const* d_in, const int* in_sizes, int n_in,
                              void* d_out, int out_size, void* d_ws, size_t ws_size,
                              hipStream_t stream) {
    const float* h_V         = (const float*)d_in[0];
    const float* h_E         = (const float*)d_in[1];
    const float* mask_V      = (const float*)d_in[2];
    const float* mask_attend = (const float*)d_in[3];
    const float* W1w  = (const float*)d_in[4];
    const float* W1bb = (const float*)d_in[5];
    const float* W2w  = (const float*)d_in[6];
    const float* W2bb = (const float*)d_in[7];
    const float* W3w  = (const float*)d_in[8];
    const float* W3bb = (const float*)d_in[9];
    const float* ln1g = (const float*)d_in[10];
    const float* ln1b = (const float*)d_in[11];
    const float* ln2g = (const float*)d_in[12];
    const float* ln2b = (const float*)d_in[13];
    const float* Winw  = (const float*)d_in[14];
    const float* Winbb = (const float*)d_in[15];
    const float* Woutw  = (const float*)d_in[16];
    const float* Woutbb = (const float*)d_in[17];

    bf16* wsb   = (bf16*)d_ws;
    bf16* W1c   = wsb;
    bf16* W2c   = wsb + WS_W2;
    bf16* W3c   = wsb + WS_W3;
    bf16* Winc  = wsb + WS_WIN;
    bf16* Woutc = wsb + WS_WOUT;
    float* h1   = (float*)((char*)d_ws + WS_H1_BYTES);

    convert_weights<<<896, 256, 0, stream>>>(W1w, W2w, W3w, Winw, Woutw, wsb);
    msg_kernel<<<4096, 256, 0, stream>>>(h_V, h_E, mask_attend, W1c, W2c, W3c,
                                         W1bb, W2bb, W3bb, ln1g, ln1b, h1);
    ffn_kernel<<<256, 256, 0, stream>>>(h1, Winc, Woutc, Winbb, Woutbb,
                                        ln2g, ln2b, mask_V, (float*)d_out);
}

// Round 3
// 490.592 us; speedup vs baseline: 1.3086x; 1.3086x over previous
//
#include <hip/hip_runtime.h>
#include <math.h>

// ---------------------------------------------------------------------------
// DecoderLayer fused implementation (MI355X / gfx950)
//   K0: convert weights fp32 -> bf16 into ws (layouts already [n][k] row-major)
//   K1: per-node message MLP, 2 nodes/block (96 edge rows), 256 threads.
//       phase 1: LDS double-buffered staging, ONE raw s_barrier per K-step
//       (lgkmcnt(0) only -- global loads stay in flight across barriers),
//       loads for tile k+2 issued at step k, tile k+1 written to LDS after
//       step k's MFMAs. Stage stride 72 bf16 (144 B, 16B-aligned, even banks).
//   K2: FFN (128->512->128) + LN2 + mask_V
// ---------------------------------------------------------------------------

typedef __bf16 bf16;
typedef __attribute__((ext_vector_type(8))) __bf16 bf16x8;
typedef __attribute__((ext_vector_type(4))) __bf16 bf16x4;
typedef __attribute__((ext_vector_type(4))) float f32x4;

__device__ __forceinline__ bf16 f2bf(float f) {
    unsigned u = __builtin_bit_cast(unsigned, f);
    u += 0x7FFFu + ((u >> 16) & 1u);           // RTNE
    unsigned short s = (unsigned short)(u >> 16);
    return __builtin_bit_cast(bf16, s);
}

// pack two fp32 -> two bf16 (RTNE), one instruction
__device__ __forceinline__ unsigned cvt_pk_bf16(float lo, float hi) {
    unsigned r;
    asm("v_cvt_pk_bf16_f32 %0, %1, %2" : "=v"(r) : "v"(lo), "v"(hi));
    return r;
}

__device__ __forceinline__ float gelu_exact(float x) {
    return 0.5f * x * (1.0f + erff(x * 0.70710678118654752f));
}

__device__ __forceinline__ f32x4 mfma16(bf16x8 a, bf16x8 b, f32x4 c) {
    return __builtin_amdgcn_mfma_f32_16x16x32_bf16(a, b, c, 0, 0, 0);
}

// ws layout (bf16 elements unless noted):
//   W1b  @ 0       : 128*512 = 65536
//   W2b  @ 65536   : 128*128 = 16384
//   W3b  @ 81920   : 128*128 = 16384
//   Winb @ 98304   : 512*128 = 65536
//   Woutb@ 163840  : 128*512 = 65536   (total 229376 bf16 = 458752 B)
//   h1   @ byte 458752 : 4096*128 fp32 = 2 MB
#define WS_W2   65536
#define WS_W3   81920
#define WS_WIN  98304
#define WS_WOUT 163840
#define WS_TOTAL_W 229376
#define WS_H1_BYTES 458752

// ---------------------------------------------------------------------------
__global__ void convert_weights(const float* __restrict__ W1, const float* __restrict__ W2,
                                const float* __restrict__ W3, const float* __restrict__ Win,
                                const float* __restrict__ Wout, bf16* __restrict__ ws) {
    int i = blockIdx.x * 256 + threadIdx.x;
    if (i < WS_W2)              ws[i] = f2bf(W1[i]);
    else if (i < WS_W3)         ws[i] = f2bf(W2[i - WS_W2]);
    else if (i < WS_WIN)        ws[i] = f2bf(W3[i - WS_W3]);
    else if (i < WS_WOUT)       ws[i] = f2bf(Win[i - WS_WIN]);
    else if (i < WS_TOTAL_W)    ws[i] = f2bf(Wout[i - WS_WOUT]);
}

// ---------------------------------------------------------------------------
// K1: 2 nodes per block (M = 96 rows), 256 threads (4 waves).
__global__ __launch_bounds__(256, 3)
void msg_kernel(const float* __restrict__ h_V, const float* __restrict__ h_E,
                const float* __restrict__ mask_attend,
                const bf16* __restrict__ W1b, const bf16* __restrict__ W2b,
                const bf16* __restrict__ W3b,
                const float* __restrict__ b1, const float* __restrict__ b2,
                const float* __restrict__ b3,
                const float* __restrict__ ln1g, const float* __restrict__ ln1b,
                float* __restrict__ h1out) {
    // LDS: stage dbuf 2x13824 = 27648 | m1 26112  (total 53760 -> 3 blocks/CU)
    //      m2 (26112) aliases the stage dbuf; tbuf (1024) aliases m1.
    __shared__ __align__(16) char smem[53760];
    bf16*  st0  = (bf16*)smem;              // 96 x 72
    bf16*  st1  = (bf16*)(smem + 13824);    // 96 x 72
    bf16*  m2   = (bf16*)smem;              // 96 x 136 (aliases st0+st1)
    bf16*  m1   = (bf16*)(smem + 27648);    // 96 x 136
    float* tbuf = (float*)(smem + 27648);   // 256 fp32 (aliases m1)

    const int tid  = threadIdx.x;
    const int wave = tid >> 6;
    const int lane = tid & 63;
    const int q    = lane >> 4;     // quad 0..3
    const int c15  = lane & 15;
    const int g0   = blockIdx.x * 2;  // first node of this block
    const int wcol0 = wave * 32 + c15;
    const int wcol1 = wcol0 + 16;

    const int r0  = tid >> 4;   // staging row within 16-row group
    const int l16 = tid & 15;   // staging float4 index

    f32x4 zero = {0.f, 0.f, 0.f, 0.f};
    f32x4 acc[6][2];
#pragma unroll
    for (int mt = 0; mt < 6; ++mt) { acc[mt][0] = zero; acc[mt][1] = zero; }

#define STAGE_LOAD(dst_, kb_)                                                   \
    {                                                                           \
        _Pragma("unroll")                                                       \
        for (int it = 0; it < 6; ++it) {                                        \
            const int row_ = it * 16 + r0;                                      \
            const int nl_  = row_ >= 48;                                        \
            const float* src_ = ((kb_) < 2)                                     \
                ? (h_V + (size_t)(g0 + nl_) * 128 + (kb_) * 64 + l16 * 4)       \
                : (h_E + (size_t)((g0 + nl_) * 48 + row_ - 48 * nl_) * 384 + (kb_) * 64 - 128 + l16 * 4); \
            dst_[it] = *(const float4*)src_;                                    \
        }                                                                       \
    }

#define STAGE_WRITE(buf_, src_)                                                 \
    {                                                                           \
        _Pragma("unroll")                                                       \
        for (int it = 0; it < 6; ++it) {                                        \
            const int row_ = it * 16 + r0;                                      \
            uint2 w_;                                                           \
            w_.x = cvt_pk_bf16(src_[it].x, src_[it].y);                         \
            w_.y = cvt_pk_bf16(src_[it].z, src_[it].w);                         \
            *(uint2*)((buf_) + row_ * 72 + l16 * 4) = w_;                       \
        }                                                                       \
    }

#define LD_W(w00_, w01_, w10_, w11_, kb_)                                       \
    {                                                                           \
        w00_ = *(const bf16x8*)(W1b + (size_t)wcol0 * 512 + (kb_) * 64 + q * 8);      \
        w01_ = *(const bf16x8*)(W1b + (size_t)wcol0 * 512 + (kb_) * 64 + 32 + q * 8); \
        w10_ = *(const bf16x8*)(W1b + (size_t)wcol1 * 512 + (kb_) * 64 + q * 8);      \
        w11_ = *(const bf16x8*)(W1b + (size_t)wcol1 * 512 + (kb_) * 64 + 32 + q * 8); \
    }

#define MFMA_STEP(stb_, w00_, w01_, w10_, w11_)                                 \
    {                                                                           \
        __builtin_amdgcn_s_setprio(1);                                          \
        _Pragma("unroll")                                                       \
        for (int mt = 0; mt < 6; ++mt) {                                        \
            bf16x8 a0_ = *(const bf16x8*)((stb_) + (mt * 16 + c15) * 72 + q * 8);      \
            bf16x8 a1_ = *(const bf16x8*)((stb_) + (mt * 16 + c15) * 72 + 32 + q * 8); \
            acc[mt][0] = mfma16(a0_, w00_, acc[mt][0]);                         \
            acc[mt][0] = mfma16(a1_, w01_, acc[mt][0]);                         \
            acc[mt][1] = mfma16(a0_, w10_, acc[mt][1]);                         \
            acc[mt][1] = mfma16(a1_, w11_, acc[mt][1]);                         \
        }                                                                       \
        __builtin_amdgcn_s_setprio(0);                                          \
    }

    // raw barrier: drain only LDS ops; global loads stay in flight (no vmcnt!)
#define BAR() { asm volatile("s_waitcnt lgkmcnt(0)" ::: "memory"); __builtin_amdgcn_s_barrier(); }

    // ---------------- phase 1 (1 barrier / step, loads 2 tiles in flight) ----
    {
        float4 rA[6], rB[6];
        bf16x8 w00, w01, w10, w11;

        STAGE_LOAD(rA, 0);
        STAGE_LOAD(rB, 1);
        STAGE_WRITE(st0, rA);
        BAR();
        // step 0: compute t0(st0); load t2; write t1->st1
        STAGE_LOAD(rA, 2);
        LD_W(w00, w01, w10, w11, 0);
        MFMA_STEP(st0, w00, w01, w10, w11);
        STAGE_WRITE(st1, rB);
        BAR();
        // step 1
        STAGE_LOAD(rB, 3);
        LD_W(w00, w01, w10, w11, 1);
        MFMA_STEP(st1, w00, w01, w10, w11);
        STAGE_WRITE(st0, rA);
        BAR();
        // step 2
        STAGE_LOAD(rA, 4);
        LD_W(w00, w01, w10, w11, 2);
        MFMA_STEP(st0, w00, w01, w10, w11);
        STAGE_WRITE(st1, rB);
        BAR();
        // step 3
        STAGE_LOAD(rB, 5);
        LD_W(w00, w01, w10, w11, 3);
        MFMA_STEP(st1, w00, w01, w10, w11);
        STAGE_WRITE(st0, rA);
        BAR();
        // step 4
        STAGE_LOAD(rA, 6);
        LD_W(w00, w01, w10, w11, 4);
        MFMA_STEP(st0, w00, w01, w10, w11);
        STAGE_WRITE(st1, rB);
        BAR();
        // step 5
        STAGE_LOAD(rB, 7);
        LD_W(w00, w01, w10, w11, 5);
        MFMA_STEP(st1, w00, w01, w10, w11);
        STAGE_WRITE(st0, rA);
        BAR();
        // step 6
        LD_W(w00, w01, w10, w11, 6);
        MFMA_STEP(st0, w00, w01, w10, w11);
        STAGE_WRITE(st1, rB);
        BAR();
        // step 7
        LD_W(w00, w01, w10, w11, 7);
        MFMA_STEP(st1, w00, w01, w10, w11);
    }
#undef BAR
#undef MFMA_STEP
#undef LD_W
#undef STAGE_WRITE
#undef STAGE_LOAD

    // epilogue 1: bias + gelu -> m1   (C/D layout: row = q*4+reg, col = c15)
    {
        const float bb0 = b1[wcol0];
        const float bb1 = b1[wcol1];
#pragma unroll
        for (int mt = 0; mt < 6; ++mt) {
#pragma unroll
            for (int r = 0; r < 4; ++r) {
                const int row = mt * 16 + q * 4 + r;
                m1[row * 136 + wcol0] = f2bf(gelu_exact(acc[mt][0][r] + bb0));
                m1[row * 136 + wcol1] = f2bf(gelu_exact(acc[mt][1][r] + bb1));
            }
        }
    }
    __syncthreads();

    // ---------------- phase 2 ----------------
#pragma unroll
    for (int mt = 0; mt < 6; ++mt) { acc[mt][0] = zero; acc[mt][1] = zero; }
    __builtin_amdgcn_s_setprio(1);
#pragma unroll
    for (int s = 0; s < 4; ++s) {
        const bf16x8 w0 = *(const bf16x8*)(W2b + (size_t)wcol0 * 128 + s * 32 + q * 8);
        const bf16x8 w1 = *(const bf16x8*)(W2b + (size_t)wcol1 * 128 + s * 32 + q * 8);
#pragma unroll
        for (int mt = 0; mt < 6; ++mt) {
            bf16x8 af = *(const bf16x8*)(m1 + (mt * 16 + c15) * 136 + s * 32 + q * 8);
            acc[mt][0] = mfma16(af, w0, acc[mt][0]);
            acc[mt][1] = mfma16(af, w1, acc[mt][1]);
        }
    }
    __builtin_amdgcn_s_setprio(0);
    {
        const float bb0 = b2[wcol0];
        const float bb1 = b2[wcol1];
#pragma unroll
        for (int mt = 0; mt < 6; ++mt) {
#pragma unroll
            for (int r = 0; r < 4; ++r) {
                const int row = mt * 16 + q * 4 + r;
                m2[row * 136 + wcol0] = f2bf(gelu_exact(acc[mt][0][r] + bb0));
                m2[row * 136 + wcol1] = f2bf(gelu_exact(acc[mt][1][r] + bb1));
            }
        }
    }
    __syncthreads();

    // ---------------- phase 3 ----------------
#pragma unroll
    for (int mt = 0; mt < 6; ++mt) { acc[mt][0] = zero; acc[mt][1] = zero; }
    __builtin_amdgcn_s_setprio(1);
#pragma unroll
    for (int s = 0; s < 4; ++s) {
        const bf16x8 w0 = *(const bf16x8*)(W3b + (size_t)wcol0 * 128 + s * 32 + q * 8);
        const bf16x8 w1 = *(const bf16x8*)(W3b + (size_t)wcol1 * 128 + s * 32 + q * 8);
#pragma unroll
        for (int mt = 0; mt < 6; ++mt) {
            bf16x8 af = *(const bf16x8*)(m2 + (mt * 16 + c15) * 136 + s * 32 + q * 8);
            acc[mt][0] = mfma16(af, w0, acc[mt][0]);
            acc[mt][1] = mfma16(af, w1, acc[mt][1]);
        }
    }
    __builtin_amdgcn_s_setprio(0);
    // masked sum over edges
    {
        const float bb0 = b3[wcol0];
        const float bb1 = b3[wcol1];
        float s00 = 0.f, s01 = 0.f, s10 = 0.f, s11 = 0.f;
#pragma unroll
        for (int mt = 0; mt < 6; ++mt) {
#pragma unroll
            for (int r = 0; r < 4; ++r) {
                const int row = mt * 16 + q * 4 + r;
                const int nl  = row >= 48;
                const float mv = mask_attend[(size_t)(g0 + nl) * 48 + row - 48 * nl];
                const float v0 = (acc[mt][0][r] + bb0) * mv;
                const float v1 = (acc[mt][1][r] + bb1) * mv;
                if (nl) { s10 += v0; s11 += v1; } else { s00 += v0; s01 += v1; }
            }
        }
#pragma unroll
        for (int off = 16; off <= 32; off <<= 1) {
            s00 += __shfl_xor(s00, off);
            s01 += __shfl_xor(s01, off);
            s10 += __shfl_xor(s10, off);
            s11 += __shfl_xor(s11, off);
        }
        if (lane < 16) {
            tbuf[wcol0]       = h_V[(size_t)g0 * 128 + wcol0]       + s00 * (1.0f / 30.0f);
            tbuf[wcol1]       = h_V[(size_t)g0 * 128 + wcol1]       + s01 * (1.0f / 30.0f);
            tbuf[128 + wcol0] = h_V[(size_t)(g0 + 1) * 128 + wcol0] + s10 * (1.0f / 30.0f);
            tbuf[128 + wcol1] = h_V[(size_t)(g0 + 1) * 128 + wcol1] + s11 * (1.0f / 30.0f);
        }
    }
    __syncthreads();
    // LN1: wave 0 -> node0, wave 1 -> node1
    if (wave < 2) {
        const float x0 = tbuf[wave * 128 + lane];
        const float x1 = tbuf[wave * 128 + 64 + lane];
        float sm = x0 + x1, sq = x0 * x0 + x1 * x1;
#pragma unroll
        for (int off = 1; off < 64; off <<= 1) { sm += __shfl_xor(sm, off); sq += __shfl_xor(sq, off); }
        const float mu  = sm * (1.0f / 128.0f);
        const float var = sq * (1.0f / 128.0f) - mu * mu;
        const float inv = rsqrtf(var + 1e-5f);
        const int g = g0 + wave;
        h1out[(size_t)g * 128 + lane]      = (x0 - mu) * inv * ln1g[lane]      + ln1b[lane];
        h1out[(size_t)g * 128 + 64 + lane] = (x1 - mu) * inv * ln1g[64 + lane] + ln1b[64 + lane];
    }
}

// ---------------------------------------------------------------------------
// K2: FFN + LN2 + mask_V. 16 rows per block, 256 blocks, 256 threads.
__global__ __launch_bounds__(256, 2)
void ffn_kernel(const float* __restrict__ h1, const bf16* __restrict__ Winb,
                const bf16* __restrict__ Woutb,
                const float* __restrict__ bin, const float* __restrict__ bout,
                const float* __restrict__ ln2g, const float* __restrict__ ln2b,
                const float* __restrict__ mask_V, float* __restrict__ out) {
    __shared__ __align__(16) bf16  a2[16 * 136];
    __shared__ __align__(16) bf16  ff[16 * 264];
    __shared__ __align__(16) float tb[16 * 132];

    const int tid  = threadIdx.x;
    const int wave = tid >> 6;
    const int lane = tid & 63;
    const int q    = lane >> 4;
    const int c15  = lane & 15;
    const int r0g  = blockIdx.x * 16;

    // stage h1 rows -> bf16 LDS
#pragma unroll
    for (int it = 0; it < 2; ++it) {
        const int idx = it * 256 + tid;      // 0..511 float4s
        const int row = idx >> 5;
        const int c4  = idx & 31;
        const float4 v = *(const float4*)(h1 + (size_t)(r0g + row) * 128 + c4 * 4);
        uint2 w;
        w.x = cvt_pk_bf16(v.x, v.y);
        w.y = cvt_pk_bf16(v.z, v.w);
        *(uint2*)(a2 + row * 136 + c4 * 4) = w;
    }

    f32x4 zero = {0.f, 0.f, 0.f, 0.f};
    f32x4 accB[2]; accB[0] = zero; accB[1] = zero;

    for (int p = 0; p < 2; ++p) {
        __syncthreads();
        // GEMM-a: [16,128] @ Win^T half -> gelu -> ff[16,256]
        f32x4 accA[4];
#pragma unroll
        for (int i = 0; i < 4; ++i) accA[i] = zero;
        __builtin_amdgcn_s_setprio(1);
#pragma unroll
        for (int s = 0; s < 4; ++s) {
            bf16x8 af = *(const bf16x8*)(a2 + c15 * 136 + s * 32 + q * 8);
#pragma unroll
            for (int nt = 0; nt < 4; ++nt) {
                const int n = p * 256 + wave * 64 + nt * 16 + c15;
                bf16x8 wb = *(const bf16x8*)(Winb + (size_t)n * 128 + s * 32 + q * 8);
                accA[nt] = mfma16(af, wb, accA[nt]);
            }
        }
        __builtin_amdgcn_s_setprio(0);
#pragma unroll
        for (int nt = 0; nt < 4; ++nt) {
            const int colL = wave * 64 + nt * 16 + c15;
            const float bb = bin[p * 256 + colL];
#pragma unroll
            for (int r = 0; r < 4; ++r) {
                const int row = q * 4 + r;
                ff[row * 264 + colL] = f2bf(gelu_exact(accA[nt][r] + bb));
            }
        }
        __syncthreads();
        // GEMM-b: ff[16,256] @ Wout^T half -> accB
        __builtin_amdgcn_s_setprio(1);
#pragma unroll
        for (int s = 0; s < 8; ++s) {
            bf16x8 af = *(const bf16x8*)(ff + c15 * 264 + s * 32 + q * 8);
#pragma unroll
            for (int nt = 0; nt < 2; ++nt) {
                const int n = wave * 32 + nt * 16 + c15;
                bf16x8 wb = *(const bf16x8*)(Woutb + (size_t)n * 512 + p * 256 + s * 32 + q * 8);
                accB[nt] = mfma16(af, wb, accB[nt]);
            }
        }
        __builtin_amdgcn_s_setprio(0);
    }
    // residual + bias -> tb
#pragma unroll
    for (int nt = 0; nt < 2; ++nt) {
        const int col = wave * 32 + nt * 16 + c15;
        const float bb = bout[col];
#pragma unroll
        for (int r = 0; r < 4; ++r) {
            const int row = q * 4 + r;
            tb[row * 132 + col] = accB[nt][r] + bb + h1[(size_t)(r0g + row) * 128 + col];
        }
    }
    __syncthreads();
    // LN2 + mask: wave w handles rows 4w..4w+3
#pragma unroll
    for (int rr = 0; rr < 4; ++rr) {
        const int row = wave * 4 + rr;
        const float x0 = tb[row * 132 + lane];
        const float x1 = tb[row * 132 + 64 + lane];
        float sm = x0 + x1, sq = x0 * x0 + x1 * x1;
#pragma unroll
        for (int off = 1; off < 64; off <<= 1) { sm += __shfl_xor(sm, off); sq += __shfl_xor(sq, off); }
        const float mu  = sm * (1.0f / 128.0f);
        const float var = sq * (1.0f / 128.0f) - mu * mu;
        const float inv = rsqrtf(var + 1e-5f);
        const int g = r0g + row;
        const float mv = mask_V[g];
        out[(size_t)g * 128 + lane]      = mv * ((x0 - mu) * inv * ln2g[lane]      + ln2b[lane]);
        out[(size_t)g * 128 + 64 + lane] = mv * ((x1 - mu) * inv * ln2g[64 + lane] + ln2b[64 + lane]);
    }
}

// ---------------------------------------------------------------------------
extern "C" void kernel_launch(void* const* d_in, const int* in_sizes, int n_in,
                              void* d_out, int out_size, void* d_ws, size_t ws_size,
                              hipStream_t stream) {
    const float* h_V         = (const float*)d_in[0];
    const float* h_E         = (const float*)d_in[1];
    const float* mask_V      = (const float*)d_in[2];
    const float* mask_attend = (const float*)d_in[3];
    const float* W1w  = (const float*)d_in[4];
    const float* W1bb = (const float*)d_in[5];
    const float* W2w  = (const float*)d_in[6];
    const float* W2bb = (const float*)d_in[7];
    const float* W3w  = (const float*)d_in[8];
    const float* W3bb = (const float*)d_in[9];
    const float* ln1g = (const float*)d_in[10];
    const float* ln1b = (const float*)d_in[11];
    const float* ln2g = (const float*)d_in[12];
    const float* ln2b = (const float*)d_in[13];
    const float* Winw  = (const float*)d_in[14];
    const float* Winbb = (const float*)d_in[15];
    const float* Woutw  = (const float*)d_in[16];
    const float* Woutbb = (const float*)d_in[17];

    bf16* wsb   = (bf16*)d_ws;
    bf16* W1c   = wsb;
    bf16* W2c   = wsb + WS_W2;
    bf16* W3c   = wsb + WS_W3;
    bf16* Winc  = wsb + WS_WIN;
    bf16* Woutc = wsb + WS_WOUT;
    float* h1   = (float*)((char*)d_ws + WS_H1_BYTES);

    convert_weights<<<896, 256, 0, stream>>>(W1w, W2w, W3w, Winw, Woutw, wsb);
    msg_kernel<<<2048, 256, 0, stream>>>(h_V, h_E, mask_attend, W1c, W2c, W3c,
                                         W1bb, W2bb, W3bb, ln1g, ln1b, h1);
    ffn_kernel<<<256, 256, 0, stream>>>(h1, Winc, Woutc, Winbb, Woutbb,
                                        ln2g, ln2b, mask_V, (float*)d_out);
}

// Round 5
// 476.046 us; speedup vs baseline: 1.3486x; 1.0306x over previous
//
#include <hip/hip_runtime.h>
#include <math.h>

// ---------------------------------------------------------------------------
// DecoderLayer fused implementation (MI355X / gfx950)
//   K0: convert weights fp32 -> bf16 into ws (layouts already [n][k] row-major)
//   K1: per-node message MLP, 2 nodes/block (96 edge rows), 256 threads.
//       phase 1: LDS double-buffered staging, ONE raw s_barrier per K-step.
//       Load-issue order: W(k+1) (L2) issued BEFORE E(k+2) (HBM) so the MFMA's
//       vmcnt wait for W(k) never drains the in-flight E tiles.
//   K2: FFN (128->512->128) + LN2 + mask_V. 512 blocks x 8 rows, single FF
//       pass. ff stride 520 (fixes R4's 264-stride aliasing bug); a2 rows
//       8..15 mirror rows 0..7 so no uninitialized LDS reaches an MFMA.
// ---------------------------------------------------------------------------

typedef __bf16 bf16;
typedef __attribute__((ext_vector_type(8))) __bf16 bf16x8;
typedef __attribute__((ext_vector_type(4))) __bf16 bf16x4;
typedef __attribute__((ext_vector_type(4))) float f32x4;

__device__ __forceinline__ bf16 f2bf(float f) {
    unsigned u = __builtin_bit_cast(unsigned, f);
    u += 0x7FFFu + ((u >> 16) & 1u);           // RTNE
    unsigned short s = (unsigned short)(u >> 16);
    return __builtin_bit_cast(bf16, s);
}

// pack two fp32 -> two bf16 (RTNE), one instruction
__device__ __forceinline__ unsigned cvt_pk_bf16(float lo, float hi) {
    unsigned r;
    asm("v_cvt_pk_bf16_f32 %0, %1, %2" : "=v"(r) : "v"(lo), "v"(hi));
    return r;
}

__device__ __forceinline__ float gelu_exact(float x) {
    return 0.5f * x * (1.0f + erff(x * 0.70710678118654752f));
}

__device__ __forceinline__ f32x4 mfma16(bf16x8 a, bf16x8 b, f32x4 c) {
    return __builtin_amdgcn_mfma_f32_16x16x32_bf16(a, b, c, 0, 0, 0);
}

// ws layout (bf16 elements unless noted):
//   W1b  @ 0       : 128*512 = 65536
//   W2b  @ 65536   : 128*128 = 16384
//   W3b  @ 81920   : 128*128 = 16384
//   Winb @ 98304   : 512*128 = 65536
//   Woutb@ 163840  : 128*512 = 65536   (total 229376 bf16 = 458752 B)
//   h1   @ byte 458752 : 4096*128 fp32 = 2 MB
#define WS_W2   65536
#define WS_W3   81920
#define WS_WIN  98304
#define WS_WOUT 163840
#define WS_TOTAL_W 229376
#define WS_H1_BYTES 458752

// ---------------------------------------------------------------------------
__global__ void convert_weights(const float* __restrict__ W1, const float* __restrict__ W2,
                                const float* __restrict__ W3, const float* __restrict__ Win,
                                const float* __restrict__ Wout, bf16* __restrict__ ws) {
    int i = blockIdx.x * 256 + threadIdx.x;
    if (i < WS_W2)              ws[i] = f2bf(W1[i]);
    else if (i < WS_W3)         ws[i] = f2bf(W2[i - WS_W2]);
    else if (i < WS_WIN)        ws[i] = f2bf(W3[i - WS_W3]);
    else if (i < WS_WOUT)       ws[i] = f2bf(Win[i - WS_WIN]);
    else if (i < WS_TOTAL_W)    ws[i] = f2bf(Wout[i - WS_WOUT]);
}

// ---------------------------------------------------------------------------
// K1: 2 nodes per block (M = 96 rows), 256 threads (4 waves).
__global__ __launch_bounds__(256, 3)
void msg_kernel(const float* __restrict__ h_V, const float* __restrict__ h_E,
                const float* __restrict__ mask_attend,
                const bf16* __restrict__ W1b, const bf16* __restrict__ W2b,
                const bf16* __restrict__ W3b,
                const float* __restrict__ b1, const float* __restrict__ b2,
                const float* __restrict__ b3,
                const float* __restrict__ ln1g, const float* __restrict__ ln1b,
                float* __restrict__ h1out) {
    // LDS: stage dbuf 2x13824 = 27648 | m1 26112  (total 53760 -> 3 blocks/CU)
    //      m2 (26112) aliases the stage dbuf; tbuf (1024) aliases m1.
    __shared__ __align__(16) char smem[53760];
    bf16*  st0  = (bf16*)smem;              // 96 x 72
    bf16*  st1  = (bf16*)(smem + 13824);    // 96 x 72
    bf16*  m2   = (bf16*)smem;              // 96 x 136 (aliases st0+st1)
    bf16*  m1   = (bf16*)(smem + 27648);    // 96 x 136
    float* tbuf = (float*)(smem + 27648);   // 256 fp32 (aliases m1)

    const int tid  = threadIdx.x;
    const int wave = tid >> 6;
    const int lane = tid & 63;
    const int q    = lane >> 4;     // quad 0..3
    const int c15  = lane & 15;
    const int g0   = blockIdx.x * 2;  // first node of this block
    const int wcol0 = wave * 32 + c15;
    const int wcol1 = wcol0 + 16;

    const int r0  = tid >> 4;   // staging row within 16-row group
    const int l16 = tid & 15;   // staging float4 index

    f32x4 zero = {0.f, 0.f, 0.f, 0.f};
    f32x4 acc[6][2];
#pragma unroll
    for (int mt = 0; mt < 6; ++mt) { acc[mt][0] = zero; acc[mt][1] = zero; }

#define STAGE_LOAD(dst_, kb_)                                                   \
    {                                                                           \
        _Pragma("unroll")                                                       \
        for (int it = 0; it < 6; ++it) {                                        \
            const int row_ = it * 16 + r0;                                      \
            const int nl_  = row_ >= 48;                                        \
            const float* src_ = ((kb_) < 2)                                     \
                ? (h_V + (size_t)(g0 + nl_) * 128 + (kb_) * 64 + l16 * 4)       \
                : (h_E + (size_t)((g0 + nl_) * 48 + row_ - 48 * nl_) * 384 + (kb_) * 64 - 128 + l16 * 4); \
            dst_[it] = *(const float4*)src_;                                    \
        }                                                                       \
    }

#define STAGE_WRITE(buf_, src_)                                                 \
    {                                                                           \
        _Pragma("unroll")                                                       \
        for (int it = 0; it < 6; ++it) {                                        \
            const int row_ = it * 16 + r0;                                      \
            uint2 w_;                                                           \
            w_.x = cvt_pk_bf16(src_[it].x, src_[it].y);                         \
            w_.y = cvt_pk_bf16(src_[it].z, src_[it].w);                         \
            *(uint2*)((buf_) + row_ * 72 + l16 * 4) = w_;                       \
        }                                                                       \
    }

#define LD_W(w00_, w01_, w10_, w11_, kb_)                                       \
    {                                                                           \
        w00_ = *(const bf16x8*)(W1b + (size_t)wcol0 * 512 + (kb_) * 64 + q * 8);      \
        w01_ = *(const bf16x8*)(W1b + (size_t)wcol0 * 512 + (kb_) * 64 + 32 + q * 8); \
        w10_ = *(const bf16x8*)(W1b + (size_t)wcol1 * 512 + (kb_) * 64 + q * 8);      \
        w11_ = *(const bf16x8*)(W1b + (size_t)wcol1 * 512 + (kb_) * 64 + 32 + q * 8); \
    }

#define MFMA_STEP(stb_, w00_, w01_, w10_, w11_)                                 \
    {                                                                           \
        __builtin_amdgcn_s_setprio(1);                                          \
        _Pragma("unroll")                                                       \
        for (int mt = 0; mt < 6; ++mt) {                                        \
            bf16x8 a0_ = *(const bf16x8*)((stb_) + (mt * 16 + c15) * 72 + q * 8);      \
            bf16x8 a1_ = *(const bf16x8*)((stb_) + (mt * 16 + c15) * 72 + 32 + q * 8); \
            acc[mt][0] = mfma16(a0_, w00_, acc[mt][0]);                         \
            acc[mt][0] = mfma16(a1_, w01_, acc[mt][0]);                         \
            acc[mt][1] = mfma16(a0_, w10_, acc[mt][1]);                         \
            acc[mt][1] = mfma16(a1_, w11_, acc[mt][1]);                         \
        }                                                                       \
        __builtin_amdgcn_s_setprio(0);                                          \
    }

    // raw barrier: drain only LDS ops; global loads stay in flight (no vmcnt!)
#define BAR() { asm volatile("s_waitcnt lgkmcnt(0)" ::: "memory"); __builtin_amdgcn_s_barrier(); }

    // ---------------- phase 1 ----------------
    // Issue-order discipline: within each step, W(k+1) [L2-fast] is issued
    // BEFORE E(k+2) [HBM]. MFMA(k)'s vmcnt wait targets W(k), which was
    // issued before E(k+1) -> E tiles are never drained early.
    {
        float4 rA[6], rB[6];
        bf16x8 wc0, wc1, wc2, wc3, wn0, wn1, wn2, wn3;

        STAGE_LOAD(rA, 0);              // E(0)
        LD_W(wc0, wc1, wc2, wc3, 0);    // W(0)  (before E(1))
        STAGE_LOAD(rB, 1);              // E(1)
        STAGE_WRITE(st0, rA);           // waits E(0) only
        BAR();
        // step 0
        LD_W(wn0, wn1, wn2, wn3, 1);    // W(1) first
        STAGE_LOAD(rA, 2);              // E(2)
        MFMA_STEP(st0, wc0, wc1, wc2, wc3);
        STAGE_WRITE(st1, rB);           // waits E(1); E(2)+W(1) stay in flight
        BAR();
        // step 1
        LD_W(wc0, wc1, wc2, wc3, 2);
        STAGE_LOAD(rB, 3);
        MFMA_STEP(st1, wn0, wn1, wn2, wn3);
        STAGE_WRITE(st0, rA);
        BAR();
        // step 2
        LD_W(wn0, wn1, wn2, wn3, 3);
        STAGE_LOAD(rA, 4);
        MFMA_STEP(st0, wc0, wc1, wc2, wc3);
        STAGE_WRITE(st1, rB);
        BAR();
        // step 3
        LD_W(wc0, wc1, wc2, wc3, 4);
        STAGE_LOAD(rB, 5);
        MFMA_STEP(st1, wn0, wn1, wn2, wn3);
        STAGE_WRITE(st0, rA);
        BAR();
        // step 4
        LD_W(wn0, wn1, wn2, wn3, 5);
        STAGE_LOAD(rA, 6);
        MFMA_STEP(st0, wc0, wc1, wc2, wc3);
        STAGE_WRITE(st1, rB);
        BAR();
        // step 5
        LD_W(wc0, wc1, wc2, wc3, 6);
        STAGE_LOAD(rB, 7);
        MFMA_STEP(st1, wn0, wn1, wn2, wn3);
        STAGE_WRITE(st0, rA);
        BAR();
        // step 6 (no more E tiles)
        LD_W(wn0, wn1, wn2, wn3, 7);
        MFMA_STEP(st0, wc0, wc1, wc2, wc3);
        STAGE_WRITE(st1, rB);
        BAR();
        // step 7
        MFMA_STEP(st1, wn0, wn1, wn2, wn3);
    }
#undef BAR
#undef MFMA_STEP
#undef LD_W
#undef STAGE_WRITE
#undef STAGE_LOAD

    // epilogue 1: bias + gelu -> m1   (C/D layout: row = q*4+reg, col = c15)
    {
        const float bb0 = b1[wcol0];
        const float bb1 = b1[wcol1];
#pragma unroll
        for (int mt = 0; mt < 6; ++mt) {
#pragma unroll
            for (int r = 0; r < 4; ++r) {
                const int row = mt * 16 + q * 4 + r;
                m1[row * 136 + wcol0] = f2bf(gelu_exact(acc[mt][0][r] + bb0));
                m1[row * 136 + wcol1] = f2bf(gelu_exact(acc[mt][1][r] + bb1));
            }
        }
    }
    __syncthreads();

    // ---------------- phase 2 ----------------
#pragma unroll
    for (int mt = 0; mt < 6; ++mt) { acc[mt][0] = zero; acc[mt][1] = zero; }
    __builtin_amdgcn_s_setprio(1);
#pragma unroll
    for (int s = 0; s < 4; ++s) {
        const bf16x8 w0 = *(const bf16x8*)(W2b + (size_t)wcol0 * 128 + s * 32 + q * 8);
        const bf16x8 w1 = *(const bf16x8*)(W2b + (size_t)wcol1 * 128 + s * 32 + q * 8);
#pragma unroll
        for (int mt = 0; mt < 6; ++mt) {
            bf16x8 af = *(const bf16x8*)(m1 + (mt * 16 + c15) * 136 + s * 32 + q * 8);
            acc[mt][0] = mfma16(af, w0, acc[mt][0]);
            acc[mt][1] = mfma16(af, w1, acc[mt][1]);
        }
    }
    __builtin_amdgcn_s_setprio(0);
    {
        const float bb0 = b2[wcol0];
        const float bb1 = b2[wcol1];
#pragma unroll
        for (int mt = 0; mt < 6; ++mt) {
#pragma unroll
            for (int r = 0; r < 4; ++r) {
                const int row = mt * 16 + q * 4 + r;
                m2[row * 136 + wcol0] = f2bf(gelu_exact(acc[mt][0][r] + bb0));
                m2[row * 136 + wcol1] = f2bf(gelu_exact(acc[mt][1][r] + bb1));
            }
        }
    }
    __syncthreads();

    // ---------------- phase 3 ----------------
#pragma unroll
    for (int mt = 0; mt < 6; ++mt) { acc[mt][0] = zero; acc[mt][1] = zero; }
    __builtin_amdgcn_s_setprio(1);
#pragma unroll
    for (int s = 0; s < 4; ++s) {
        const bf16x8 w0 = *(const bf16x8*)(W3b + (size_t)wcol0 * 128 + s * 32 + q * 8);
        const bf16x8 w1 = *(const bf16x8*)(W3b + (size_t)wcol1 * 128 + s * 32 + q * 8);
#pragma unroll
        for (int mt = 0; mt < 6; ++mt) {
            bf16x8 af = *(const bf16x8*)(m2 + (mt * 16 + c15) * 136 + s * 32 + q * 8);
            acc[mt][0] = mfma16(af, w0, acc[mt][0]);
            acc[mt][1] = mfma16(af, w1, acc[mt][1]);
        }
    }
    __builtin_amdgcn_s_setprio(0);
    // masked sum over edges
    {
        const float bb0 = b3[wcol0];
        const float bb1 = b3[wcol1];
        float s00 = 0.f, s01 = 0.f, s10 = 0.f, s11 = 0.f;
#pragma unroll
        for (int mt = 0; mt < 6; ++mt) {
#pragma unroll
            for (int r = 0; r < 4; ++r) {
                const int row = mt * 16 + q * 4 + r;
                const int nl  = row >= 48;
                const float mv = mask_attend[(size_t)(g0 + nl) * 48 + row - 48 * nl];
                const float v0 = (acc[mt][0][r] + bb0) * mv;
                const float v1 = (acc[mt][1][r] + bb1) * mv;
                if (nl) { s10 += v0; s11 += v1; } else { s00 += v0; s01 += v1; }
            }
        }
#pragma unroll
        for (int off = 16; off <= 32; off <<= 1) {
            s00 += __shfl_xor(s00, off);
            s01 += __shfl_xor(s01, off);
            s10 += __shfl_xor(s10, off);
            s11 += __shfl_xor(s11, off);
        }
        if (lane < 16) {
            tbuf[wcol0]       = h_V[(size_t)g0 * 128 + wcol0]       + s00 * (1.0f / 30.0f);
            tbuf[wcol1]       = h_V[(size_t)g0 * 128 + wcol1]       + s01 * (1.0f / 30.0f);
            tbuf[128 + wcol0] = h_V[(size_t)(g0 + 1) * 128 + wcol0] + s10 * (1.0f / 30.0f);
            tbuf[128 + wcol1] = h_V[(size_t)(g0 + 1) * 128 + wcol1] + s11 * (1.0f / 30.0f);
        }
    }
    __syncthreads();
    // LN1: wave 0 -> node0, wave 1 -> node1
    if (wave < 2) {
        const float x0 = tbuf[wave * 128 + lane];
        const float x1 = tbuf[wave * 128 + 64 + lane];
        float sm = x0 + x1, sq = x0 * x0 + x1 * x1;
#pragma unroll
        for (int off = 1; off < 64; off <<= 1) { sm += __shfl_xor(sm, off); sq += __shfl_xor(sq, off); }
        const float mu  = sm * (1.0f / 128.0f);
        const float var = sq * (1.0f / 128.0f) - mu * mu;
        const float inv = rsqrtf(var + 1e-5f);
        const int g = g0 + wave;
        h1out[(size_t)g * 128 + lane]      = (x0 - mu) * inv * ln1g[lane]      + ln1b[lane];
        h1out[(size_t)g * 128 + 64 + lane] = (x1 - mu) * inv * ln1g[64 + lane] + ln1b[64 + lane];
    }
}

// ---------------------------------------------------------------------------
// K2: FFN + LN2 + mask_V. 8 rows per block, 512 blocks, 256 threads.
//   Single pass over FF=512, 3 barriers. ff stride 520 (>=512, 16B-aligned,
//   rows 4 banks apart). a2 rows 8..15 mirror rows 0..7 (no garbage in MFMA);
//   output rows 8..15 of the M=16 tiles are discarded.
__global__ __launch_bounds__(256, 4)
void ffn_kernel(const float* __restrict__ h1, const bf16* __restrict__ Winb,
                const bf16* __restrict__ Woutb,
                const float* __restrict__ bin, const float* __restrict__ bout,
                const float* __restrict__ ln2g, const float* __restrict__ ln2b,
                const float* __restrict__ mask_V, float* __restrict__ out) {
    __shared__ __align__(16) bf16  a2[16 * 136];   // rows 8..15 = copy of 0..7
    __shared__ __align__(16) bf16  ff[16 * 520];   // rows 8..15 = dup results
    __shared__ __align__(16) float tb[8 * 132];

    const int tid  = threadIdx.x;
    const int wave = tid >> 6;
    const int lane = tid & 63;
    const int q    = lane >> 4;
    const int c15  = lane & 15;
    const int r0g  = blockIdx.x * 8;

    // stage 8 h1 rows -> bf16 LDS (one float4 per thread); mirror into rows 8..15
    {
        const int row = tid >> 5;
        const int c4  = tid & 31;
        const float4 v = *(const float4*)(h1 + (size_t)(r0g + row) * 128 + c4 * 4);
        uint2 w;
        w.x = cvt_pk_bf16(v.x, v.y);
        w.y = cvt_pk_bf16(v.z, v.w);
        *(uint2*)(a2 + row * 136 + c4 * 4)       = w;
        *(uint2*)(a2 + (row + 8) * 136 + c4 * 4) = w;
    }
    __syncthreads();

    f32x4 zero = {0.f, 0.f, 0.f, 0.f};

    // GEMM-a: [8,128] @ Win^T -> gelu -> ff[8,512]; wave covers 128 FF cols
    f32x4 accA[8];
#pragma unroll
    for (int i = 0; i < 8; ++i) accA[i] = zero;
    __builtin_amdgcn_s_setprio(1);
#pragma unroll
    for (int s = 0; s < 4; ++s) {
        bf16x8 af = *(const bf16x8*)(a2 + c15 * 136 + s * 32 + q * 8);
#pragma unroll
        for (int nt = 0; nt < 8; ++nt) {
            const int n = wave * 128 + nt * 16 + c15;
            bf16x8 wb = *(const bf16x8*)(Winb + (size_t)n * 128 + s * 32 + q * 8);
            accA[nt] = mfma16(af, wb, accA[nt]);
        }
    }
    __builtin_amdgcn_s_setprio(0);
#pragma unroll
    for (int nt = 0; nt < 8; ++nt) {
        const int colL = wave * 128 + nt * 16 + c15;
        const float bb = bin[colL];
#pragma unroll
        for (int r = 0; r < 4; ++r) {
            const int row = q * 4 + r;
            ff[row * 520 + colL] = f2bf(gelu_exact(accA[nt][r] + bb));
        }
    }
    __syncthreads();

    // GEMM-b: ff[8,512] @ Wout^T -> out cols wave*32 + nt*16 + c15
    f32x4 accB[2]; accB[0] = zero; accB[1] = zero;
    __builtin_amdgcn_s_setprio(1);
#pragma unroll
    for (int s = 0; s < 16; ++s) {
        bf16x8 af = *(const bf16x8*)(ff + c15 * 520 + s * 32 + q * 8);
#pragma unroll
        for (int nt = 0; nt < 2; ++nt) {
            const int n = wave * 32 + nt * 16 + c15;
            bf16x8 wb = *(const bf16x8*)(Woutb + (size_t)n * 512 + s * 32 + q * 8);
            accB[nt] = mfma16(af, wb, accB[nt]);
        }
    }
    __builtin_amdgcn_s_setprio(0);

    // residual + bias -> tb (rows 0..7 only)
#pragma unroll
    for (int nt = 0; nt < 2; ++nt) {
        const int col = wave * 32 + nt * 16 + c15;
        const float bb = bout[col];
#pragma unroll
        for (int r = 0; r < 4; ++r) {
            const int row = q * 4 + r;
            if (row < 8)
                tb[row * 132 + col] = accB[nt][r] + bb + h1[(size_t)(r0g + row) * 128 + col];
        }
    }
    __syncthreads();

    // LN2 + mask: wave w handles rows 2w, 2w+1
#pragma unroll
    for (int rr = 0; rr < 2; ++rr) {
        const int row = wave * 2 + rr;
        const float x0 = tb[row * 132 + lane];
        const float x1 = tb[row * 132 + 64 + lane];
        float sm = x0 + x1, sq = x0 * x0 + x1 * x1;
#pragma unroll
        for (int off = 1; off < 64; off <<= 1) { sm += __shfl_xor(sm, off); sq += __shfl_xor(sq, off); }
        const float mu  = sm * (1.0f / 128.0f);
        const float var = sq * (1.0f / 128.0f) - mu * mu;
        const float inv = rsqrtf(var + 1e-5f);
        const int g = r0g + row;
        const float mv = mask_V[g];
        out[(size_t)g * 128 + lane]      = mv * ((x0 - mu) * inv * ln2g[lane]      + ln2b[lane]);
        out[(size_t)g * 128 + 64 + lane] = mv * ((x1 - mu) * inv * ln2g[64 + lane] + ln2b[64 + lane]);
    }
}

// ---------------------------------------------------------------------------
extern "C" void kernel_launch(void* const* d_in, const int* in_sizes, int n_in,
                              void* d_out, int out_size, void* d_ws, size_t ws_size,
                              hipStream_t stream) {
    const float* h_V         = (const float*)d_in[0];
    const float* h_E         = (const float*)d_in[1];
    const float* mask_V      = (const float*)d_in[2];
    const float* mask_attend = (const float*)d_in[3];
    const float* W1w  = (const float*)d_in[4];
    const float* W1bb = (const float*)d_in[5];
    const float* W2w  = (const float*)d_in[6];
    const float* W2bb = (const float*)d_in[7];
    const float* W3w  = (const float*)d_in[8];
    const float* W3bb = (const float*)d_in[9];
    const float* ln1g = (const float*)d_in[10];
    const float* ln1b = (const float*)d_in[11];
    const float* ln2g = (const float*)d_in[12];
    const float* ln2b = (const float*)d_in[13];
    const float* Winw  = (const float*)d_in[14];
    const float* Winbb = (const float*)d_in[15];
    const float* Woutw  = (const float*)d_in[16];
    const float* Woutbb = (const float*)d_in[17];

    bf16* wsb   = (bf16*)d_ws;
    bf16* W1c   = wsb;
    bf16* W2c   = wsb + WS_W2;
    bf16* W3c   = wsb + WS_W3;
    bf16* Winc  = wsb + WS_WIN;
    bf16* Woutc = wsb + WS_WOUT;
    float* h1   = (float*)((char*)d_ws + WS_H1_BYTES);

    convert_weights<<<896, 256, 0, stream>>>(W1w, W2w, W3w, Winw, Woutw, wsb);
    msg_kernel<<<2048, 256, 0, stream>>>(h_V, h_E, mask_attend, W1c, W2c, W3c,
                                         W1bb, W2bb, W3bb, ln1g, ln1b, h1);
    ffn_kernel<<<512, 256, 0, stream>>>(h1, Winc, Woutc, Winbb, Woutbb,
                                        ln2g, ln2b, mask_V, (float*)d_out);
}